// Round 6
// baseline (55.840 us; speedup 1.0000x reference)
//
#include <hip/hip_runtime.h>
#include <hip/hip_fp16.h>

// HalutMatmul forward on MI355X — two-kernel split (round 6).
// Per row n: h[c][p] = sum_d I[n, c*9+d] * A[c][d][p]   (c=0..15, p=0..3)
//            code_c  = 4-level tree descent: bit_l = (h[c][l] > T[c*15 + node_l])
//            out[n][m] = sum_c L[m][c][code_c]
//
// Round-5 diagnosis: monolithic kernel is latency-bound on the serial chain
// (I-load -> f64 hash -> dependent tree loads -> gather) at 16 waves/CU.
// Split: K1 = hash+tree -> packed codes in d_ws (6.5 KB LDS, high occupancy);
//        K2 = LUT gather + transpose store (no f64, ~write-BW-bound).

#define NROWS (1024 * 128)

// ---------------------------------------------------------------- K1: codes
__global__ __launch_bounds__(256, 4) void halut_codes(
    const float* __restrict__ I,
    const float* __restrict__ A,
    const float* __restrict__ T,
    uint32_t* __restrict__ codes)
{
    __shared__ double sA[576];   // A promoted to f64: [c][d][p]
    __shared__ double sT[240];   // thresholds, f64

    const int tid = threadIdx.x;
    for (int i = tid; i < 576; i += 256) sA[i] = (double)A[i];
    if (tid < 240) sT[tid] = (double)T[tid];
    __syncthreads();

    const int lr  = tid >> 1;            // local row 0..127
    const int mh  = tid & 1;             // which 8 codebooks
    const int row = blockIdx.x * 128 + lr;
    const float* rp = I + (size_t)row * 144 + mh * 72;

    uint32_t mycodes = 0;
    #pragma unroll
    for (int g = 0; g < 2; ++g) {                    // 4 codebooks per group
        float4 buf[9];
        const float4* rv = (const float4*)(rp + g * 36);  // 16B-aligned
        #pragma unroll
        for (int i = 0; i < 9; ++i) buf[i] = rv[i];
        const float* bf = (const float*)buf;

        #pragma unroll
        for (int cc = 0; cc < 4; ++cc) {
            const int cl = g * 4 + cc;               // 0..7 local codebook
            const int c  = mh * 8 + cl;              // global codebook
            double h0 = 0.0, h1 = 0.0, h2 = 0.0, h3 = 0.0;
            #pragma unroll
            for (int d = 0; d < 9; ++d) {
                const double  x  = (double)bf[cc * 9 + d];
                const double* ap = &sA[(c * 9 + d) * 4];
                h0 = fma(x, ap[0], h0);
                h1 = fma(x, ap[1], h1);
                h2 = fma(x, ap[2], h2);
                h3 = fma(x, ap[3], h3);
            }
            const double* tp = &sT[c * 15];
            int p;
            p =         (h0 > tp[0]);
            p = 2 * p + (h1 > tp[1 + p]);
            p = 2 * p + (h2 > tp[3 + p]);
            p = 2 * p + (h3 > tp[7 + p]);
            mycodes |= (uint32_t)p << (4 * cl);
        }
    }
    // coalesced: codes[2*row + mh] == codes[blockIdx.x*256 + tid]
    codes[blockIdx.x * 256 + tid] = mycodes;
}

// --------------------------------------------------------------- K2: gather
__global__ __launch_bounds__(256, 4) void halut_gather(
    const float* __restrict__ L,
    const uint32_t* __restrict__ codes,
    float* __restrict__ out)
{
    // 32 KiB: f16 LUT, uint2[q8][col]: q8 = m/4 (0..15), col = c*16+p (0..255);
    // dword x = halves (m=4q8, 4q8+1), dword y = (4q8+2, 4q8+3).
    // Reused as float[128][64] output staging after the gather.
    __shared__ uint32_t sBuf[8192];

    const int tid = threadIdx.x;

    {   // ---- stage L: thread t owns column col = t; coalesced loads ----
        uint2* lut2 = (uint2*)sBuf;
        #pragma unroll
        for (int q = 0; q < 16; ++q) {
            const float a = L[(4 * q + 0) * 256 + tid];
            const float b = L[(4 * q + 1) * 256 + tid];
            const float c = L[(4 * q + 2) * 256 + tid];
            const float d = L[(4 * q + 3) * 256 + tid];
            uint2 u;
            u.x = ((uint32_t)__half_as_ushort(__float2half_rn(b)) << 16)
                |  (uint32_t)__half_as_ushort(__float2half_rn(a));
            u.y = ((uint32_t)__half_as_ushort(__float2half_rn(d)) << 16)
                |  (uint32_t)__half_as_ushort(__float2half_rn(c));
            lut2[q * 256 + tid] = u;
        }
    }
    __syncthreads();

    const int lr  = tid >> 1;            // local row 0..127
    const int mh  = tid & 1;             // which half of m
    const int row = blockIdx.x * 128 + lr;

    const uint2 cw = ((const uint2*)codes)[row];   // pairs share addr (bcast)
    const uint32_t lo = cw.x;            // codes c=0..7
    const uint32_t hi = cw.y;            // codes c=8..15

    __half2 acc2[16];
    const __half2 zero = __floats2half2_rn(0.f, 0.f);
    #pragma unroll
    for (int k = 0; k < 16; ++k) acc2[k] = zero;

    const uint2* lut2 = (const uint2*)sBuf;
    #pragma unroll 4
    for (int c = 0; c < 16; ++c) {
        const int p   = (int)(((c < 8 ? lo : hi) >> (4 * (c & 7))) & 15u);
        const int col = (c << 4) + p;
        #pragma unroll
        for (int i = 0; i < 8; ++i) {            // q8 = mh*8+i -> m quad
            const uint2 w = lut2[((mh * 8 + i) << 8) + col];
            const __half2 w0 = *(const __half2*)&w.x;
            const __half2 w1 = *(const __half2*)&w.y;
            acc2[2 * i]     = __hadd2(acc2[2 * i],     w0);
            acc2[2 * i + 1] = __hadd2(acc2[2 * i + 1], w1);
        }
    }

    // ---- single-pass output transpose through sBuf (LUT is dead now) ----
    __syncthreads();
    float* sO = (float*)sBuf;            // [128 rows][64 m], 16B-chunk swizzle
    #pragma unroll
    for (int k2 = 0; k2 < 8; ++k2) {
        const int ch = mh * 8 + k2;      // global float4 chunk = m/4
        const float4 v = make_float4(__low2float(acc2[2 * k2]),
                                     __high2float(acc2[2 * k2]),
                                     __low2float(acc2[2 * k2 + 1]),
                                     __high2float(acc2[2 * k2 + 1]));
        *(float4*)&sO[(lr << 6) + ((ch ^ (lr & 15)) << 2)] = v;
    }
    __syncthreads();

    float4* op = (float4*)(out + (size_t)blockIdx.x * (128 * 64));
    #pragma unroll
    for (int j = 0; j < 8; ++j) {        // 2048 float4 = 32 KiB, contiguous
        const int F  = tid + (j << 8);
        const int r2 = F >> 4;
        const int m2 = F & 15;
        op[F] = *(const float4*)&sO[(r2 << 6) + ((m2 ^ (r2 & 15)) << 2)];
    }
}

extern "C" void kernel_launch(void* const* d_in, const int* in_sizes, int n_in,
                              void* d_out, int out_size, void* d_ws, size_t ws_size,
                              hipStream_t stream) {
    const float* I = (const float*)d_in[0];
    const float* A = (const float*)d_in[1];
    const float* T = (const float*)d_in[2];
    const float* L = (const float*)d_in[3];
    float* outp = (float*)d_out;
    uint32_t* codes = (uint32_t*)d_ws;   // 2 x uint32 per row = 1 MiB

    const int nblocks = NROWS / 128;     // 1024 blocks x 256 threads, 2 thr/row
    halut_codes <<<nblocks, 256, 0, stream>>>(I, A, T, codes);
    halut_gather<<<nblocks, 256, 0, stream>>>(L, codes, outp);
}

// Round 7
// 31.485 us; speedup vs baseline: 1.7735x; 1.7735x over previous
//
#include <hip/hip_runtime.h>
#include <hip/hip_fp16.h>

// HalutMatmul forward on MI355X.
// Per row n: h[c][p] = sum_d I[n, c*9+d] * A[c][d][p]   (c=0..15, p=0..3)
//            code_c  = 4-level tree descent: bit_l = (h[c][l] > T[c*15 + node_l])
//            out[n][m] = sum_c L[m][c][code_c]
//
// Round-7: LDS-pipe attack (rounds 3-6 shared a ~22us/CU LDS-issue floor):
//  - A staged as f32, read as float4 b128 broadcasts (9/cb instead of 36 b64);
//    f32->f64 cvt is exact so the f64 hash is unchanged.
//  - Parallel 15-threshold compare (T f32 padded [c][16], 4 b128 broadcasts)
//    -> decision mask + register bit-chase. No p-dependent LDS loads, no
//    divergent-address bank conflicts, no 4x120cyc serial chain.
//  - Round-5 gather (f16 b64, 2-way-free, hadd2) + swizzled transpose epilogue.

#define NROWS (1024 * 128)

__global__ __launch_bounds__(256, 3) void halut_fwd(
    const float* __restrict__ I,
    const float* __restrict__ A,
    const float* __restrict__ T,
    const float* __restrict__ L,
    float* __restrict__ out)
{
    // 32 KiB: f16 LUT, uint2[q8][col]: q8 = m/4 (0..15), col = c*16+p (0..255);
    // dword x = halves (m=4q8, 4q8+1), dword y = (4q8+2, 4q8+3).
    // Reused as float[128][64] output staging after the gather.
    __shared__ uint32_t sBuf[8192];
    __shared__ float    sA[576];   // A f32 [c][d][p] (b128-readable)
    __shared__ float    sT[256];   // T f32 padded [c][16]

    const int tid = threadIdx.x;

    {   // ---- stage L: thread t owns column col = t; coalesced loads ----
        uint2* lut2 = (uint2*)sBuf;
        #pragma unroll
        for (int q = 0; q < 16; ++q) {
            const float a = L[(4 * q + 0) * 256 + tid];
            const float b = L[(4 * q + 1) * 256 + tid];
            const float c = L[(4 * q + 2) * 256 + tid];
            const float d = L[(4 * q + 3) * 256 + tid];
            uint2 u;
            u.x = ((uint32_t)__half_as_ushort(__float2half_rn(b)) << 16)
                |  (uint32_t)__half_as_ushort(__float2half_rn(a));
            u.y = ((uint32_t)__half_as_ushort(__float2half_rn(d)) << 16)
                |  (uint32_t)__half_as_ushort(__float2half_rn(c));
            lut2[q * 256 + tid] = u;
        }
    }
    for (int i = tid; i < 576; i += 256) sA[i] = A[i];
    {   // T padded: 16 slots per codebook, slot 15 unused
        const int c = tid >> 4, j = tid & 15;
        sT[tid] = (j < 15) ? T[c * 15 + j] : 0.0f;
    }
    __syncthreads();

    const int lr  = tid >> 1;            // local row 0..127
    const int mh  = tid & 1;             // which half of m / which 8 codebooks
    const int row = blockIdx.x * 128 + lr;
    const float* rp = I + (size_t)row * 144 + mh * 72;

    // ---- load my 72 input floats in one burst (VMEM ILP) ----
    float4 buf[18];
    {
        const float4* rv = (const float4*)rp;   // 288B offset -> 16B aligned
        #pragma unroll
        for (int i = 0; i < 18; ++i) buf[i] = rv[i];
    }
    const float* bf = (const float*)buf;

    // ---- hash + parallel-threshold tree for my 8 codebooks ----
    uint32_t mycodes = 0;
    #pragma unroll
    for (int cl = 0; cl < 8; ++cl) {
        const int c = mh * 8 + cl;               // global codebook
        double h0 = 0.0, h1 = 0.0, h2 = 0.0, h3 = 0.0;
        #pragma unroll
        for (int d = 0; d < 9; ++d) {
            const double x  = (double)bf[cl * 9 + d];
            const float4 av = *(const float4*)&sA[(c * 9 + d) * 4];
            h0 = fma(x, (double)av.x, h0);
            h1 = fma(x, (double)av.y, h1);
            h2 = fma(x, (double)av.z, h2);
            h3 = fma(x, (double)av.w, h3);
        }
        // all 15 node compares, no dependent loads
        const float4 ta = *(const float4*)&sT[c * 16 + 0];   // nodes 0..3
        const float4 tb = *(const float4*)&sT[c * 16 + 4];   // nodes 4..7
        const float4 tc = *(const float4*)&sT[c * 16 + 8];   // nodes 8..11
        const float4 td = *(const float4*)&sT[c * 16 + 12];  // nodes 12..14
        uint32_t mk = 0;
        mk |= (h0 > (double)ta.x) ?     1u : 0u;   // node 0  (level 0)
        mk |= (h1 > (double)ta.y) ?     2u : 0u;   // node 1  (level 1)
        mk |= (h1 > (double)ta.z) ?     4u : 0u;   // node 2
        mk |= (h2 > (double)ta.w) ?     8u : 0u;   // node 3  (level 2)
        mk |= (h2 > (double)tb.x) ?    16u : 0u;   // node 4
        mk |= (h2 > (double)tb.y) ?    32u : 0u;   // node 5
        mk |= (h2 > (double)tb.z) ?    64u : 0u;   // node 6
        mk |= (h3 > (double)tb.w) ?   128u : 0u;   // node 7  (level 3)
        mk |= (h3 > (double)tc.x) ?   256u : 0u;   // node 8
        mk |= (h3 > (double)tc.y) ?   512u : 0u;   // node 9
        mk |= (h3 > (double)tc.z) ?  1024u : 0u;   // node 10
        mk |= (h3 > (double)tc.w) ?  2048u : 0u;   // node 11
        mk |= (h3 > (double)td.x) ?  4096u : 0u;   // node 12
        mk |= (h3 > (double)td.y) ?  8192u : 0u;   // node 13
        mk |= (h3 > (double)td.z) ? 16384u : 0u;   // node 14
        int p =       (int)(mk & 1u);
        p = 2 * p + (int)((mk >> (1 + p)) & 1u);
        p = 2 * p + (int)((mk >> (3 + p)) & 1u);
        p = 2 * p + (int)((mk >> (7 + p)) & 1u);
        mycodes |= (uint32_t)p << (4 * cl);
    }
    const uint32_t other = __shfl_xor(mycodes, 1);   // partner's 8 codes
    const uint32_t lo = mh ? other : mycodes;        // codes c=0..7
    const uint32_t hi = mh ? mycodes : other;        // codes c=8..15

    // ---- gather-accumulate my 32 m-values (packed-half adds) ----
    __half2 acc2[16];
    const __half2 zero = __floats2half2_rn(0.f, 0.f);
    #pragma unroll
    for (int k = 0; k < 16; ++k) acc2[k] = zero;

    const uint2* lut2 = (const uint2*)sBuf;
    #pragma unroll 4
    for (int c = 0; c < 16; ++c) {
        const int p   = (int)(((c < 8 ? lo : hi) >> (4 * (c & 7))) & 15u);
        const int col = (c << 4) + p;
        #pragma unroll
        for (int i = 0; i < 8; ++i) {            // q8 = mh*8+i -> m quad
            const uint2 w = lut2[((mh * 8 + i) << 8) + col];
            const __half2 w0 = *(const __half2*)&w.x;
            const __half2 w1 = *(const __half2*)&w.y;
            acc2[2 * i]     = __hadd2(acc2[2 * i],     w0);
            acc2[2 * i + 1] = __hadd2(acc2[2 * i + 1], w1);
        }
    }

    // ---- single-pass output transpose through sBuf (LUT is dead now) ----
    __syncthreads();
    float* sO = (float*)sBuf;            // [128 rows][64 m], 16B-chunk swizzle
    #pragma unroll
    for (int k2 = 0; k2 < 8; ++k2) {
        const int ch = mh * 8 + k2;      // global float4 chunk = m/4
        const float4 v = make_float4(__low2float(acc2[2 * k2]),
                                     __high2float(acc2[2 * k2]),
                                     __low2float(acc2[2 * k2 + 1]),
                                     __high2float(acc2[2 * k2 + 1]));
        *(float4*)&sO[(lr << 6) + ((ch ^ (lr & 15)) << 2)] = v;
    }
    __syncthreads();

    float4* op = (float4*)(out + (size_t)blockIdx.x * (128 * 64));
    #pragma unroll
    for (int j = 0; j < 8; ++j) {        // 2048 float4 = 32 KiB, contiguous
        const int F  = tid + (j << 8);
        const int r2 = F >> 4;
        const int m2 = F & 15;
        op[F] = *(const float4*)&sO[(r2 << 6) + ((m2 ^ (r2 & 15)) << 2)];
    }
}

extern "C" void kernel_launch(void* const* d_in, const int* in_sizes, int n_in,
                              void* d_out, int out_size, void* d_ws, size_t ws_size,
                              hipStream_t stream) {
    const float* I = (const float*)d_in[0];
    const float* A = (const float*)d_in[1];
    const float* T = (const float*)d_in[2];
    const float* L = (const float*)d_in[3];
    float* outp = (float*)d_out;

    const int nblocks = NROWS / 128;   // 1024 blocks x 256 threads, 2 thr/row
    halut_fwd<<<nblocks, 256, 0, stream>>>(I, A, T, L, outp);
}

// Round 8
// 30.505 us; speedup vs baseline: 1.8305x; 1.0321x over previous
//
#include <hip/hip_runtime.h>
#include <hip/hip_fp16.h>

// HalutMatmul forward on MI355X.
// Per row n: h[c][p] = sum_d I[n, c*9+d] * A[c][d][p]   (c=0..15, p=0..3)
//            code_c  = 4-level tree descent: bit_l = (h[c][l] > T[c*15 + node_l])
//            out[n][m] = sum_c L[m][c][code_c]
//
// Round-8: pipe-overlap attack. Rounds 3/5/7 all ~30us = SUM of VALU(~12us)
// + LDS(~8us) + VMEM(~7us) because barrier-lockstepped phases never overlap.
// This version: 1 thread/row, per-codebook pipeline hash(c)->code(c)->gather(c)
// with rolling I prefetch, so all three pipes are live concurrently.
//  - A/T in LDS as f64, read as wave-UNIFORM double2 broadcasts (free-ish).
//  - f16 LUT uint4[m/8][col]; 8 ds_read_b128/cb, 16-distinct-slot = 2-way free.
//  - Round-3 epilogue (measured 0 conflicts), wave-uniform halves.

#define NROWS (1024 * 128)

__global__ __launch_bounds__(256, 2) void halut_fwd(
    const float* __restrict__ I,
    const float* __restrict__ A,
    const float* __restrict__ T,
    const float* __restrict__ L,
    float* __restrict__ out)
{
    // 32 KiB: f16 LUT uint4[q=0..7][col=0..255], col = c*16+p; uint4 dword e
    // holds m = (8q+2e, 8q+2e+1). Reused as float[128][64] epilogue staging.
    __shared__ uint32_t sBuf[8192];
    __shared__ double   sA[576];   // A f64 [c][d][p]
    __shared__ double   sT[256];   // T f64 padded [c][16]

    const int tid = threadIdx.x;

    {   // ---- stage LUT: thread t owns column col = t; coalesced loads ----
        uint4* lut4 = (uint4*)sBuf;
        #pragma unroll
        for (int q = 0; q < 8; ++q) {
            uint32_t w[4];
            #pragma unroll
            for (int e = 0; e < 4; ++e) {
                const float fa = L[(8 * q + 2 * e)     * 256 + tid];
                const float fb = L[(8 * q + 2 * e + 1) * 256 + tid];
                w[e] = ((uint32_t)__half_as_ushort(__float2half_rn(fb)) << 16)
                     |  (uint32_t)__half_as_ushort(__float2half_rn(fa));
            }
            lut4[q * 256 + tid] = make_uint4(w[0], w[1], w[2], w[3]);
        }
    }
    for (int i = tid; i < 576; i += 256) sA[i] = (double)A[i];
    {   // T padded to 16 slots per codebook
        const int c = tid >> 4, j = tid & 15;
        sT[tid] = (j < 15) ? (double)T[c * 15 + j] : 0.0;
    }
    __syncthreads();

    const int row = blockIdx.x * 256 + tid;          // 1 thread = 1 row
    const float* rp = I + (size_t)row * 144;

    __half2 acc2[32];
    #pragma unroll
    for (int k = 0; k < 32; ++k) acc2[k] = __floats2half2_rn(0.f, 0.f);

    const uint4* lut4 = (const uint4*)sBuf;

    float4 bufA[9], bufB[9];
    #pragma unroll
    for (int i = 0; i < 9; ++i) bufA[i] = ((const float4*)rp)[i];

    #pragma unroll
    for (int g = 0; g < 4; ++g) {                    // 4 codebooks per group
        const float* curp = (const float*)((g & 1) ? bufB : bufA);
        if (g < 3) {                                 // rolling prefetch (VMEM)
            float4* nxt = (g & 1) ? bufA : bufB;
            const float4* src = (const float4*)(rp + (g + 1) * 36);
            #pragma unroll
            for (int i = 0; i < 9; ++i) nxt[i] = src[i];
        }
        #pragma unroll
        for (int cc = 0; cc < 4; ++cc) {
            const int c = g * 4 + cc;                // uniform + literal
            // ---- f64 hash; A via wave-uniform double2 broadcasts ----
            double h0 = 0.0, h1 = 0.0, h2 = 0.0, h3 = 0.0;
            #pragma unroll
            for (int d = 0; d < 9; ++d) {
                const double  x   = (double)curp[cc * 9 + d];
                const double2 a01 = *(const double2*)&sA[(c * 9 + d) * 4];
                const double2 a23 = *(const double2*)&sA[(c * 9 + d) * 4 + 2];
                h0 = fma(x, a01.x, h0);
                h1 = fma(x, a01.y, h1);
                h2 = fma(x, a23.x, h2);
                h3 = fma(x, a23.y, h3);
            }
            // ---- parallel 15-threshold compare (uniform broadcasts) ----
            const double2* tp = (const double2*)&sT[c * 16];
            const double2 t0 = tp[0], t1 = tp[1], t2 = tp[2], t3 = tp[3];
            const double2 t4 = tp[4], t5 = tp[5], t6 = tp[6], t7 = tp[7];
            uint32_t mk = 0;
            mk |= (h0 > t0.x) ?     1u : 0u;   // node 0  (level 0)
            mk |= (h1 > t0.y) ?     2u : 0u;   // node 1  (level 1)
            mk |= (h1 > t1.x) ?     4u : 0u;   // node 2
            mk |= (h2 > t1.y) ?     8u : 0u;   // node 3  (level 2)
            mk |= (h2 > t2.x) ?    16u : 0u;   // node 4
            mk |= (h2 > t2.y) ?    32u : 0u;   // node 5
            mk |= (h2 > t3.x) ?    64u : 0u;   // node 6
            mk |= (h3 > t3.y) ?   128u : 0u;   // node 7  (level 3)
            mk |= (h3 > t4.x) ?   256u : 0u;   // node 8
            mk |= (h3 > t4.y) ?   512u : 0u;   // node 9
            mk |= (h3 > t5.x) ?  1024u : 0u;   // node 10
            mk |= (h3 > t5.y) ?  2048u : 0u;   // node 11
            mk |= (h3 > t6.x) ?  4096u : 0u;   // node 12
            mk |= (h3 > t6.y) ?  8192u : 0u;   // node 13
            mk |= (h3 > t7.x) ? 16384u : 0u;   // node 14
            int p =       (int)(mk & 1u);
            p = 2 * p + (int)((mk >> (1 + p)) & 1u);
            p = 2 * p + (int)((mk >> (3 + p)) & 1u);
            p = 2 * p + (int)((mk >> (7 + p)) & 1u);

            // ---- gather cb c: 8 x ds_read_b128, 16-slot spread = 2-way free ----
            const uint4* colp = lut4 + (c << 4) + p;
            #pragma unroll
            for (int q = 0; q < 8; ++q) {
                const uint4 w = colp[q << 8];
                acc2[q * 4 + 0] = __hadd2(acc2[q * 4 + 0], *(const __half2*)&w.x);
                acc2[q * 4 + 1] = __hadd2(acc2[q * 4 + 1], *(const __half2*)&w.y);
                acc2[q * 4 + 2] = __hadd2(acc2[q * 4 + 2], *(const __half2*)&w.z);
                acc2[q * 4 + 3] = __hadd2(acc2[q * 4 + 3], *(const __half2*)&w.w);
            }
        }
    }

    // ---- epilogue: round-3 pattern (measured 0 conflicts), 2 x 128 rows ----
    __syncthreads();                     // LUT dead
    float* sO = (float*)sBuf;            // [128 rows][64 m], 16B-chunk swizzle
    #pragma unroll
    for (int half = 0; half < 2; ++half) {
        if ((tid >> 7) == half) {        // wave-uniform branch (waves 0-1 / 2-3)
            const int r = tid & 127;
            #pragma unroll
            for (int ch = 0; ch < 16; ++ch) {
                const float4 v = make_float4(__low2float (acc2[2 * ch]),
                                             __high2float(acc2[2 * ch]),
                                             __low2float (acc2[2 * ch + 1]),
                                             __high2float(acc2[2 * ch + 1]));
                *(float4*)&sO[(r << 6) + ((ch ^ (r & 15)) << 2)] = v;
            }
        }
        __syncthreads();
        float4* op = (float4*)(out + (size_t)blockIdx.x * (256 * 64)
                                   + (size_t)half * (128 * 64));
        #pragma unroll
        for (int j = 0; j < 8; ++j) {    // 2048 float4 = 32 KiB, contiguous
            const int F  = tid + (j << 8);
            const int r2 = F >> 4;
            const int m2 = F & 15;
            op[F] = *(const float4*)&sO[(r2 << 6) + ((m2 ^ (r2 & 15)) << 2)];
        }
        __syncthreads();
    }
}

extern "C" void kernel_launch(void* const* d_in, const int* in_sizes, int n_in,
                              void* d_out, int out_size, void* d_ws, size_t ws_size,
                              hipStream_t stream) {
    const float* I = (const float*)d_in[0];
    const float* A = (const float*)d_in[1];
    const float* T = (const float*)d_in[2];
    const float* L = (const float*)d_in[3];
    float* outp = (float*)d_out;

    const int nblocks = NROWS / 256;   // 512 blocks x 256 threads, 1 thr/row
    halut_fwd<<<nblocks, 256, 0, stream>>>(I, A, T, L, outp);
}